// Round 1
// 510.080 us; speedup vs baseline: 1.3116x; 1.3116x over previous
//
#include <hip/hip_runtime.h>

// ---------------------------------------------------------------------------
// GCN 3-layer: h = relu(Agg(dinv*x@W1)+b1); h = relu(Agg(dinv*h@W2)+b2);
//              out = Agg(dinv*h@W3)+b3
// Agg(y)[d] = dinv[d] * ( sum_{e: dst=d} y[src_e] + y[d] )   (self-loop folded)
// R6: CSR construction rebuilt as a two-level LDS bucket sort.
//   fill_csr4 was 145us at 10% HBM with 107MB WRITE_SIZE (16x write
//   amplification: 1.6M random 4B scatters -> 64B lines, cross-XCD thrash).
//   New pipeline: bucket_hist -> bucket_scan -> bucket_scatter (LDS-staged,
//   coalesced pair writes) -> csr_build (per-bucket deg/scan/fill; colidx
//   writes confined to one 16KB L2-resident region per block). Also removes
//   count_deg4 (1.6M random global atomics) and the 3 node-scan kernels.
// ---------------------------------------------------------------------------

typedef __attribute__((ext_vector_type(8))) short short8;
typedef __attribute__((ext_vector_type(4))) float floatx4;

#define NBUK_MAX 512
#define SC_EDGES 6144  // edges staged per scatter block (48KB LDS)
#define HIST_EDGES 8192

__device__ __forceinline__ unsigned f2bf_bits(float f) {
    unsigned u = __float_as_uint(f);
    return (u + 0x7fffu + ((u >> 16) & 1u)) >> 16;  // RNE
}
__device__ __forceinline__ float bf_bits2f(unsigned b) {
    return __uint_as_float(b << 16);
}

__global__ __launch_bounds__(256) void zero_i32(int* p, int n) {
    int i = blockIdx.x * 256 + threadIdx.x;
    if (i < n) p[i] = 0;
}

// ---- pass 1: per-block LDS histogram of dst buckets -> global counts ----
__global__ __launch_bounds__(512) void bucket_hist(const int* __restrict__ dst,
                                                   int* __restrict__ buckcnt,
                                                   int e, int shift, int nbuk) {
    __shared__ int hist[NBUK_MAX];
    int t = threadIdx.x;
    for (int i = t; i < nbuk; i += 512) hist[i] = 0;
    __syncthreads();
    long long base = (long long)blockIdx.x * HIST_EDGES;
#pragma unroll
    for (int j = 0; j < HIST_EDGES / 512; j++) {
        long long i = base + j * 512 + t;
        if (i < e) atomicAdd(&hist[dst[i] >> shift], 1);
    }
    __syncthreads();
    for (int i = t; i < nbuk; i += 512)
        if (hist[i] > 0) atomicAdd(&buckcnt[i], hist[i]);
}

// ---- pass 2: scan bucket counts -> bucket offsets (and fill cursors) ----
__global__ __launch_bounds__(512) void bucket_scan(const int* __restrict__ buckcnt,
                                                   int* __restrict__ boff,
                                                   int* __restrict__ buckfill,
                                                   int* __restrict__ rowptr,
                                                   int nbuk, int n, int e) {
    __shared__ int sc[512];
    int t = threadIdx.x;
    int v = (t < nbuk) ? buckcnt[t] : 0;
    sc[t] = v;
    __syncthreads();
    for (int off = 1; off < 512; off <<= 1) {
        int u = (t >= off) ? sc[t - off] : 0;
        __syncthreads();
        sc[t] += u;
        __syncthreads();
    }
    int excl = sc[t] - v;
    if (t < nbuk) {
        boff[t] = excl;
        buckfill[t] = excl;
    }
    if (t == 0) {
        boff[nbuk] = e;
        rowptr[n] = e;
    }
}

// ---- pass 3: bin (src,dst) pairs into bucket-contiguous colpair array ----
// LDS-staged in bucket-sorted order, then linear copy-out -> coalesced writes.
__global__ __launch_bounds__(512) void bucket_scatter(const int* __restrict__ src,
                                                      const int* __restrict__ dst,
                                                      int* __restrict__ buckfill,
                                                      int2* __restrict__ colpair,
                                                      int e, int shift, int nbuk) {
    __shared__ int hist[NBUK_MAX];
    __shared__ int lscan[NBUK_MAX];  // preserved block-local exclusive offsets
    __shared__ int fillL[NBUK_MAX];  // running fill cursors
    __shared__ int baseG[NBUK_MAX];  // reserved global base per bucket
    __shared__ int2 stage[SC_EDGES];
    int t = threadIdx.x;
    for (int i = t; i < nbuk; i += 512) hist[i] = 0;
    __syncthreads();
    long long base = (long long)blockIdx.x * SC_EDGES;
#pragma unroll
    for (int j = 0; j < SC_EDGES / 512; j++) {
        long long i = base + j * 512 + t;
        if (i < e) atomicAdd(&hist[dst[i] >> shift], 1);
    }
    __syncthreads();
    // exclusive scan of per-block histogram (Hillis-Steele over 512)
    int v = (t < nbuk) ? hist[t] : 0;
    lscan[t] = v;
    __syncthreads();
    for (int off = 1; off < 512; off <<= 1) {
        int u = (t >= off) ? lscan[t - off] : 0;
        __syncthreads();
        lscan[t] += u;
        __syncthreads();
    }
    int excl = lscan[t] - v;
    lscan[t] = excl;
    fillL[t] = excl;
    if (t < nbuk && v > 0) baseG[t] = atomicAdd(&buckfill[t], v);
    __syncthreads();
    // place pairs into LDS in bucket-sorted order
#pragma unroll
    for (int j = 0; j < SC_EDGES / 512; j++) {
        long long i = base + j * 512 + t;
        if (i < e) {
            int d = dst[i];
            int s = src[i];
            int p = atomicAdd(&fillL[d >> shift], 1);
            stage[p] = make_int2(s, d);
        }
    }
    __syncthreads();
    // linear copy-out: consecutive slots share buckets -> coalesced runs
    long long rem = (long long)e - base;
    int cnt = (rem < SC_EDGES) ? (int)rem : SC_EDGES;
    for (int k = t; k < cnt; k += 512) {
        int2 pr = stage[k];
        int b = pr.y >> shift;
        colpair[baseG[b] + (k - lscan[b])] = pr;
    }
}

// ---- pass 4: per-bucket CSR build: deg, rowptr, dinv, colidx ----
// All colidx writes land in this bucket's contiguous region (~16KB): single
// XCD owns it, L2-resident, one clean writeback.
__global__ __launch_bounds__(512) void csr_build(const int2* __restrict__ colpair,
                                                 const int* __restrict__ boff,
                                                 int* __restrict__ rowptr,
                                                 float* __restrict__ dinv,
                                                 int* __restrict__ colidx,
                                                 int n, int shift) {
    __shared__ int degl[NBUK_MAX];
    __shared__ int lsc[NBUK_MAX];
    __shared__ int fill[NBUK_MAX];
    int t = threadIdx.x;
    int bn = 1 << shift;
    int node0 = blockIdx.x << shift;
    int e0 = boff[blockIdx.x];
    int e1 = boff[blockIdx.x + 1];
    if (t < bn) degl[t] = 0;
    __syncthreads();
    for (int i = e0 + t; i < e1; i += 512)
        atomicAdd(&degl[colpair[i].y - node0], 1);
    __syncthreads();
    int v = (t < bn) ? degl[t] : 0;
    lsc[t] = v;
    __syncthreads();
    for (int off = 1; off < 512; off <<= 1) {
        int u = (t >= off) ? lsc[t - off] : 0;
        __syncthreads();
        lsc[t] += u;
        __syncthreads();
    }
    int excl = lsc[t] - v;
    int node = node0 + t;
    if (t < bn && node < n) {
        rowptr[node] = e0 + excl;
        dinv[node] = rsqrtf((float)(v + 1));
    }
    fill[t] = e0 + excl;
    __syncthreads();
    for (int i = e0 + t; i < e1; i += 512) {
        int2 pr = colpair[i];
        int p = atomicAdd(&fill[pr.y - node0], 1);
        colidx[p] = pr.x;
    }
}

// ---- W1 split into hi/lo bf16, pre-swizzled into B-fragment order ----
// B-frag for 16x16x32: lane holds B[k=quad*8+j][n=lane&15], quad=lane>>4.
// Storage: whi[((ct*16+kc)*64+lane)*8 + j], ct=n>>4, kc=k>>5.
__global__ __launch_bounds__(256) void w1_split(const float* __restrict__ W1,
                                                short* __restrict__ whi,
                                                short* __restrict__ wlo) {
    int idx = blockIdx.x * 256 + threadIdx.x;  // 0..32767
    int k = idx >> 6;
    int nn = idx & 63;
    float v = W1[idx];
    unsigned hb = f2bf_bits(v);
    float lof = v - bf_bits2f(hb);
    unsigned lb = f2bf_bits(lof);
    int kc = k >> 5, rem = k & 31, quad = rem >> 3, j = rem & 7;
    int ct = nn >> 4, l = nn & 15;
    int lane = quad * 16 + l;
    int addr = ((ct * 16 + kc) * 64 + lane) * 8 + j;
    whi[addr] = (short)hb;
    wlo[addr] = (short)lb;
}

// ---- transform 1 (MFMA): h1 = dinv .* (x @ W1), x:(n,512) W1:(512,64) ----
// 64 rows x 64 cols per block (4 waves; wave w -> rows w*16..w*16+15, all 64
// cols as 4 col-tiles). Split-bf16: x = ahi + alo; 3 MFMAs (hi*hi, lo*hi,
// hi*lo) recover fp32 accuracy to ~2^-16 input rounding.
__global__ __launch_bounds__(256) void transform1_mfma(const float* __restrict__ x,
                                                       const short* __restrict__ whi,
                                                       const short* __restrict__ wlo,
                                                       const float* __restrict__ dinv,
                                                       float* __restrict__ h1, int n) {
    __shared__ float xs[64 * 36];  // [m][k] row-major, stride 36 (144B, 16B-aligned)
    const int t = threadIdx.x;
    const int w = t >> 6;
    const int lane = t & 63;
    const int quad = lane >> 4;
    const int row0 = blockIdx.x * 64;
    const int mrow = w * 16 + (lane & 15);  // A-frag row within block tile
    floatx4 acc[4] = {{0.f, 0.f, 0.f, 0.f}, {0.f, 0.f, 0.f, 0.f},
                      {0.f, 0.f, 0.f, 0.f}, {0.f, 0.f, 0.f, 0.f}};

    for (int kc = 0; kc < 16; kc++) {
        __syncthreads();
        // stage x tile: 64 rows x 32 k = 512 float4
#pragma unroll
        for (int i = 0; i < 2; i++) {
            int c = t + i * 256;
            int m = c >> 3;
            int koff = (c & 7) << 2;
            int grow = row0 + m;
            float4 v = make_float4(0.f, 0.f, 0.f, 0.f);
            if (grow < n) v = *(const float4*)&x[(size_t)grow * 512 + kc * 32 + koff];
            *(float4*)&xs[m * 36 + koff] = v;
        }
        __syncthreads();
        // A fragment: 8 consecutive k at row mrow, k-offset quad*8
        float a[8];
        *(float4*)&a[0] = *(const float4*)&xs[mrow * 36 + quad * 8];
        *(float4*)&a[4] = *(const float4*)&xs[mrow * 36 + quad * 8 + 4];
        short8 ahi, alo;
#pragma unroll
        for (int j = 0; j < 8; j++) {
            unsigned hb = f2bf_bits(a[j]);
            float lof = a[j] - bf_bits2f(hb);
            unsigned lb = f2bf_bits(lof);
            ahi[j] = (short)hb;
            alo[j] = (short)lb;
        }
        const int base = (kc * 64 + lane) * 8;  // + ct*8192
#pragma unroll
        for (int ct = 0; ct < 4; ct++) {
            short8 bhi = *(const short8*)&whi[ct * 8192 + base];
            short8 blo = *(const short8*)&wlo[ct * 8192 + base];
            acc[ct] = __builtin_amdgcn_mfma_f32_16x16x32_bf16(ahi, bhi, acc[ct], 0, 0, 0);
            acc[ct] = __builtin_amdgcn_mfma_f32_16x16x32_bf16(alo, bhi, acc[ct], 0, 0, 0);
            acc[ct] = __builtin_amdgcn_mfma_f32_16x16x32_bf16(ahi, blo, acc[ct], 0, 0, 0);
        }
    }
    // epilogue: D[row=quad*4+r][col=lane&15]
#pragma unroll
    for (int r = 0; r < 4; r++) {
        int grow = row0 + w * 16 + quad * 4 + r;
        if (grow < n) {
            float s = dinv[grow];
#pragma unroll
            for (int ct = 0; ct < 4; ct++) {
                h1[(size_t)grow * 64 + ct * 16 + (lane & 15)] = acc[ct][r] * s;
            }
        }
    }
}

// ---- transform 2: h2 = dinv .* (g1 @ W2), g1:(n,64) W2:(64,32) ----
__global__ __launch_bounds__(256) void transform2(const float* __restrict__ g1,
                                                  const float* __restrict__ W2,
                                                  const float* __restrict__ dinv,
                                                  float* __restrict__ h2, int n) {
    __shared__ float rows[32 * 68];
    __shared__ float W2s[64 * 32];
    int t = threadIdx.x;
    int row0 = blockIdx.x * 32;
#pragma unroll
    for (int i = 0; i < 2; i++) {          // 32 rows x 64 = 512 float4
        int c = t + i * 256;
        int r = c >> 4, k4 = (c & 15) << 2;
        int grow = row0 + r;
        float4 v = make_float4(0.f, 0.f, 0.f, 0.f);
        if (grow < n) v = *(const float4*)&g1[(size_t)grow * 64 + k4];
        *(float4*)&rows[r * 68 + k4] = v;
    }
#pragma unroll
    for (int i = 0; i < 2; i++) {          // W2: 2048 floats = 512 float4
        int c = t + i * 256;
        *(float4*)&W2s[c * 4] = *(const float4*)&W2[c * 4];
    }
    __syncthreads();
    int lr = t >> 3;                       // 0..31 (row)
    int c4 = (t & 7) * 4;                  // 0,4,...,28 (col group)
    int row = row0 + lr;
    float a0 = 0.f, a1 = 0.f, a2 = 0.f, a3 = 0.f;
#pragma unroll
    for (int k4 = 0; k4 < 64; k4 += 4) {
        float4 a = *(const float4*)&rows[lr * 68 + k4];
        float4 w0 = *(const float4*)&W2s[(k4 + 0) * 32 + c4];
        float4 w1 = *(const float4*)&W2s[(k4 + 1) * 32 + c4];
        float4 w2 = *(const float4*)&W2s[(k4 + 2) * 32 + c4];
        float4 w3 = *(const float4*)&W2s[(k4 + 3) * 32 + c4];
        a0 += a.x * w0.x + a.y * w1.x + a.z * w2.x + a.w * w3.x;
        a1 += a.x * w0.y + a.y * w1.y + a.z * w2.y + a.w * w3.y;
        a2 += a.x * w0.z + a.y * w1.z + a.z * w2.z + a.w * w3.z;
        a3 += a.x * w0.w + a.y * w1.w + a.z * w2.w + a.w * w3.w;
    }
    if (row < n) {
        float s = dinv[row];
        float4 o = make_float4(a0 * s, a1 * s, a2 * s, a3 * s);
        *(float4*)&h2[(size_t)row * 32 + c4] = o;
    }
}

// ---- transform 3: h3 = dinv .* (g2 @ W3), g2:(n,32) W3:(32,4). thread/row ----
__global__ __launch_bounds__(256) void transform3(const float* __restrict__ g2,
                                                  const float* __restrict__ W3,
                                                  const float* __restrict__ dinv,
                                                  float* __restrict__ h3, int n) {
    __shared__ float W3s[128];
    int t = threadIdx.x;
    if (t < 128) W3s[t] = W3[t];
    __syncthreads();
    int row = blockIdx.x * 256 + t;
    if (row >= n) return;
    float a0 = 0.f, a1 = 0.f, a2 = 0.f, a3 = 0.f;
    const float4* rp = (const float4*)&g2[(size_t)row * 32];
#pragma unroll
    for (int kk = 0; kk < 8; kk++) {
        float4 v = rp[kk];
        float4 w0 = *(const float4*)&W3s[(4 * kk + 0) * 4];
        float4 w1 = *(const float4*)&W3s[(4 * kk + 1) * 4];
        float4 w2 = *(const float4*)&W3s[(4 * kk + 2) * 4];
        float4 w3 = *(const float4*)&W3s[(4 * kk + 3) * 4];
        a0 += v.x * w0.x + v.y * w1.x + v.z * w2.x + v.w * w3.x;
        a1 += v.x * w0.y + v.y * w1.y + v.z * w2.y + v.w * w3.y;
        a2 += v.x * w0.z + v.y * w1.z + v.z * w2.z + v.w * w3.z;
        a3 += v.x * w0.w + v.y * w1.w + v.z * w2.w + v.w * w3.w;
    }
    float s = dinv[row];
    float4 o = make_float4(a0 * s, a1 * s, a2 * s, a3 * s);
    *(float4*)&h3[(size_t)row * 4] = o;
}

// ---- aggregation (ILP): F-lane group per node, 8-way edge unroll ----
template <int F, bool RELU>
__global__ __launch_bounds__(256) void aggregate_ilp(const float* __restrict__ h,
                                                     const int* __restrict__ rowptr,
                                                     const int* __restrict__ colidx,
                                                     const float* __restrict__ dinv,
                                                     const float* __restrict__ bias,
                                                     float* __restrict__ out, int n) {
    int tid = blockIdx.x * 256 + threadIdx.x;
    int node = tid / F;
    int f = tid & (F - 1);
    if (node >= n) return;
    int r0 = rowptr[node], r1 = rowptr[node + 1];
    float acc0 = h[(size_t)node * F + f];  // self loop
    float acc1 = 0.f, acc2 = 0.f, acc3 = 0.f;
    float acc4 = 0.f, acc5 = 0.f, acc6 = 0.f, acc7 = 0.f;
    int j = r0;
    for (; j + 7 < r1; j += 8) {
        int c0 = colidx[j + 0];
        int c1 = colidx[j + 1];
        int c2 = colidx[j + 2];
        int c3 = colidx[j + 3];
        int c4 = colidx[j + 4];
        int c5 = colidx[j + 5];
        int c6 = colidx[j + 6];
        int c7 = colidx[j + 7];
        acc0 += h[(size_t)c0 * F + f];
        acc1 += h[(size_t)c1 * F + f];
        acc2 += h[(size_t)c2 * F + f];
        acc3 += h[(size_t)c3 * F + f];
        acc4 += h[(size_t)c4 * F + f];
        acc5 += h[(size_t)c5 * F + f];
        acc6 += h[(size_t)c6 * F + f];
        acc7 += h[(size_t)c7 * F + f];
    }
    for (; j < r1; j++) {
        acc0 += h[(size_t)colidx[j] * F + f];
    }
    float acc = ((acc0 + acc1) + (acc2 + acc3)) + ((acc4 + acc5) + (acc6 + acc7));
    float v = dinv[node] * acc + bias[f];
    if (RELU) v = fmaxf(v, 0.f);
    out[(size_t)node * F + f] = v;
}

extern "C" void kernel_launch(void* const* d_in, const int* in_sizes, int n_in,
                              void* d_out, int out_size, void* d_ws, size_t ws_size,
                              hipStream_t stream) {
    const float* x  = (const float*)d_in[0];
    const int*   ei = (const int*)d_in[1];
    const float* W1 = (const float*)d_in[2];
    const float* b1 = (const float*)d_in[3];
    const float* W2 = (const float*)d_in[4];
    const float* b2 = (const float*)d_in[5];
    const float* W3 = (const float*)d_in[6];
    const float* b3 = (const float*)d_in[7];
    const int n = in_sizes[0] / 512;  // 100000
    const int e = in_sizes[1] / 2;    // 1600000
    const int* src = ei;
    const int* dst = ei + e;
    float* out = (float*)d_out;

    char* p = (char*)d_ws;
    auto alloc = [&](size_t bytes) {
        void* r = (void*)p;
        p += (bytes + 255) & ~(size_t)255;
        return r;
    };
    int*   buckcnt  = (int*)alloc((size_t)NBUK_MAX * 4);
    int*   boff     = (int*)alloc((size_t)(NBUK_MAX + 1) * 4);
    int*   buckfill = (int*)alloc((size_t)NBUK_MAX * 4);
    int*   rowptr   = (int*)alloc((size_t)(n + 1) * 4);
    int*   colidx   = (int*)alloc((size_t)e * 4);
    float* dinv     = (float*)alloc((size_t)n * 4);
    short* whi      = (short*)alloc((size_t)32768 * 2);
    short* wlo      = (short*)alloc((size_t)32768 * 2);
    float* bufA     = (float*)alloc((size_t)n * 64 * 4);
    float* bufB     = (float*)alloc((size_t)n * 64 * 4);
    // colpair (E x 8B = 12.8MB) aliases bufA (25.6MB): dead before transform1.
    int2*  colpair  = (int2*)bufA;

    int shift = 8;
    while (((n + (1 << shift) - 1) >> shift) > NBUK_MAX) shift++;
    const int nbuk = (n + (1 << shift) - 1) >> shift;  // 391 for n=100000

    const int HB = (int)(((long long)e + HIST_EDGES - 1) / HIST_EDGES);
    const int SB = (int)(((long long)e + SC_EDGES - 1) / SC_EDGES);

    zero_i32<<<dim3((nbuk + 255) / 256), dim3(256), 0, stream>>>(buckcnt, nbuk);
    bucket_hist<<<dim3(HB), dim3(512), 0, stream>>>(dst, buckcnt, e, shift, nbuk);
    bucket_scan<<<dim3(1), dim3(512), 0, stream>>>(buckcnt, boff, buckfill, rowptr, nbuk, n, e);
    bucket_scatter<<<dim3(SB), dim3(512), 0, stream>>>(src, dst, buckfill, colpair, e, shift, nbuk);
    csr_build<<<dim3(nbuk), dim3(512), 0, stream>>>(colpair, boff, rowptr, dinv, colidx, n, shift);
    w1_split<<<dim3(128), dim3(256), 0, stream>>>(W1, whi, wlo);

    // layer 1: transform (n,512)->(n,64), aggregate, relu
    transform1_mfma<<<dim3((n + 63) / 64), dim3(256), 0, stream>>>(x, whi, wlo, dinv, bufA, n);
    aggregate_ilp<64, true><<<dim3((int)(((size_t)n * 64 + 255) / 256)), dim3(256), 0, stream>>>(bufA, rowptr, colidx, dinv, b1, bufB, n);
    // layer 2: (n,64)->(n,32)
    transform2<<<dim3((n + 31) / 32), dim3(256), 0, stream>>>(bufB, W2, dinv, bufA, n);
    aggregate_ilp<32, true><<<dim3((int)(((size_t)n * 32 + 255) / 256)), dim3(256), 0, stream>>>(bufA, rowptr, colidx, dinv, b2, bufB, n);
    // layer 3: (n,32)->(n,4), no relu
    transform3<<<dim3((n + 255) / 256), dim3(256), 0, stream>>>(bufB, W3, dinv, bufA, n);
    aggregate_ilp<4, false><<<dim3((int)(((size_t)n * 4 + 255) / 256)), dim3(256), 0, stream>>>(bufA, rowptr, colidx, dinv, b3, out, n);
}